// Round 3
// baseline (323.281 us; speedup 1.0000x reference)
//
#include <hip/hip_runtime.h>

#define TOK 64
#define CDIM 192
#define NH 6
#define HD 32
#define NWAVE 6
#define THREADS 384
#define QSCALE 0.17677669529663687f  // 32^-0.5

// workspace layout (halfs): w_qkv16 [576*192] | w_proj16 [192*192] | bias frags [6*4*64*16]
#define WQ16_OFF 0
#define WP16_OFF 110592
#define BIAS_OFF 147456
#define WS_HALFS (147456 + 24576)
#define WS_BYTES (WS_HALFS * 2)

typedef _Float16 f16x8 __attribute__((ext_vector_type(8)));
typedef _Float16 f16x4 __attribute__((ext_vector_type(4)));
typedef float f32x4 __attribute__((ext_vector_type(4)));

__device__ __forceinline__ f16x8 ld8(const _Float16* p) {
  return *reinterpret_cast<const f16x8*>(p);
}

__device__ __forceinline__ f16x8 cvt8(const float* __restrict__ p) {
  float4 a = *reinterpret_cast<const float4*>(p);
  float4 c = *reinterpret_cast<const float4*>(p + 4);
  f16x8 r;
  r[0] = (_Float16)a.x; r[1] = (_Float16)a.y; r[2] = (_Float16)a.z; r[3] = (_Float16)a.w;
  r[4] = (_Float16)c.x; r[5] = (_Float16)c.y; r[6] = (_Float16)c.z; r[7] = (_Float16)c.w;
  return r;
}

// Prologue: fp16 weights + per-(head,row-tile) bias fragments laid out so each
// lane's 16 bias values (jt 0..3 x r 0..3) are two contiguous f16x8 loads.
__global__ void prep_ws(const float* __restrict__ wq, const float* __restrict__ wp,
                        const float* __restrict__ bt, _Float16* __restrict__ ws) {
  int i = blockIdx.x * 256 + threadIdx.x;
  if (i < 27648) {
    float4 v = reinterpret_cast<const float4*>(wq)[i];
    f16x4 h;
    h[0] = (_Float16)v.x; h[1] = (_Float16)v.y; h[2] = (_Float16)v.z; h[3] = (_Float16)v.w;
    *reinterpret_cast<f16x4*>(ws + WQ16_OFF + (size_t)i * 4) = h;
  } else if (i < 36864) {
    int j = i - 27648;
    float4 v = reinterpret_cast<const float4*>(wp)[j];
    f16x4 h;
    h[0] = (_Float16)v.x; h[1] = (_Float16)v.y; h[2] = (_Float16)v.z; h[3] = (_Float16)v.w;
    *reinterpret_cast<f16x4*>(ws + WP16_OFF + (size_t)j * 4) = h;
  } else if (i < 61440) {
    int j = i - 36864;            // ((h*4+it)*64 + lane)*16 + (jt*4+r)
    int hit = j >> 10;
    int l = (j >> 4) & 63;
    int s = j & 15;
    int h = hit >> 2, it = hit & 3;
    int ii = it * 16 + (l & 15);
    int jj = (s >> 2) * 16 + (l >> 4) * 4 + (s & 3);
    int rel = ((ii >> 3) - (jj >> 3) + 7) * 15 + ((ii & 7) - (jj & 7) + 7);
    ws[BIAS_OFF + j] = (_Float16)bt[rel * NH + h];
  }
}

// Fused window attention: 1 block = 1 window, 6 waves, 4 barriers, ~79 KB LDS
// -> 2 blocks/CU. LDS buffers overlaid (single-wave ownership after hoists):
//   A: x panels        -> v^T          (barrier-protected swap)
//   B: q panels        -> P slices     (wave w = head w owns B[w] after qf hoist)
//   C: k panels        -> attn-out O   (wave w owns C[w] after kf hoist)
// Panel layout: elem(row,k) at [(k>>3)*ROWS + row]*8 + (k&7): all MFMA
// fragment accesses are contiguous 16B ds_read_b128.
template <bool WS>
__global__ __launch_bounds__(THREADS, 3) void winattn(
    const float* __restrict__ x, const float* __restrict__ w_qkv,
    const float* __restrict__ b_qkv, const float* __restrict__ w_proj,
    const float* __restrict__ b_proj, const float* __restrict__ bias_table,
    const _Float16* __restrict__ ws, float* __restrict__ out) {
  __shared__ __align__(16) _Float16 Ab[24 * TOK * 8];  // x -> v^T
  __shared__ __align__(16) _Float16 Bb[24 * TOK * 8];  // q -> P
  __shared__ __align__(16) _Float16 Cb[24 * TOK * 8];  // k -> O
  __shared__ float bias_sm[225 * NH];                  // fallback path only

  const int tid = threadIdx.x;
  const int w   = tid >> 6;   // 0..5 (wave == head in phase 2)
  const int l   = tid & 63;
  const int l15 = l & 15;
  const int lg  = l >> 4;
  const int b   = blockIdx.x;
  const f32x4 vzero = {0.f, 0.f, 0.f, 0.f};

  // ---------------- phase 0: stage x ----------------
  const float* xg = x + (size_t)b * (TOK * CDIM);
#pragma unroll
  for (int i = tid; i < TOK * CDIM / 4; i += THREADS) {
    int n = i / (CDIM / 4);
    int c = (i % (CDIM / 4)) * 4;
    float4 v = reinterpret_cast<const float4*>(xg)[i];
    f16x4 h4;
    h4[0] = (_Float16)v.x; h4[1] = (_Float16)v.y;
    h4[2] = (_Float16)v.z; h4[3] = (_Float16)v.w;
    *reinterpret_cast<f16x4*>(&Ab[((c >> 3) * TOK + n) * 8 + (c & 7)]) = h4;
  }
  if constexpr (!WS) {
    for (int i = tid; i < 225 * NH; i += THREADS) bias_sm[i] = bias_table[i];
  }
  __syncthreads();

  // ------- phase 1: QKV GEMM (64x576, K=192); wave w -> tiles w+6g -------
  f32x4 acc[6][4];
#pragma unroll
  for (int g = 0; g < 6; ++g)
#pragma unroll
    for (int mt = 0; mt < 4; ++mt) acc[g][mt] = vzero;

#pragma unroll
  for (int ks = 0; ks < 6; ++ks) {
    f16x8 a[4];
#pragma unroll
    for (int mt = 0; mt < 4; ++mt)
      a[mt] = ld8(&Ab[((ks * 4 + lg) * TOK + mt * 16 + l15) * 8]);
#pragma unroll
    for (int g = 0; g < 6; ++g) {
      int row = (w + 6 * g) * 16 + l15;  // 0..575
      f16x8 bf;
      if constexpr (WS) bf = ld8(ws + WQ16_OFF + (size_t)row * CDIM + ks * 32 + lg * 8);
      else              bf = cvt8(w_qkv + (size_t)row * CDIM + ks * 32 + lg * 8);
#pragma unroll
      for (int mt = 0; mt < 4; ++mt)
        acc[g][mt] = __builtin_amdgcn_mfma_f32_16x16x32_f16(a[mt], bf, acc[g][mt], 0, 0, 0);
    }
  }
  // epilogue a: q -> Bb, k -> Cb (fresh buffers, no barrier needed yet)
#pragma unroll
  for (int g = 0; g < 4; ++g) {
    int row = (w + 6 * g) * 16 + l15;
    int dl = row - (g >> 1) * CDIM;       // dim within part
    int hh = dl >> 5, hd = dl & 31;
    float bq = b_qkv[row];
    _Float16* dst = (g < 2) ? Bb : Cb;
    float scale = (g < 2) ? QSCALE : 1.f;
#pragma unroll
    for (int mt = 0; mt < 4; ++mt)
#pragma unroll
      for (int r = 0; r < 4; ++r) {
        int n = mt * 16 + lg * 4 + r;
        dst[hh * 2048 + ((hd >> 3) * TOK + n) * 8 + (hd & 7)] =
            (_Float16)((acc[g][mt][r] + bq) * scale);
      }
  }
  __syncthreads();  // all x reads done -> Ab reusable
  // epilogue b: v^T -> Ab
#pragma unroll
  for (int g = 4; g < 6; ++g) {
    int row = (w + 6 * g) * 16 + l15;
    int dl = row - 2 * CDIM;
    int hh = dl >> 5, hd = dl & 31;
    float bq = b_qkv[row];
#pragma unroll
    for (int mt = 0; mt < 4; ++mt)
#pragma unroll
      for (int r = 0; r < 4; ++r) {
        int n = mt * 16 + lg * 4 + r;
        Ab[hh * 2048 + ((n >> 3) * HD + hd) * 8 + (n & 7)] = (_Float16)(acc[g][mt][r] + bq);
      }
  }
  __syncthreads();

  // ---------------- phase 2: attention, wave w = head w ----------------
  {
    // hoist all q/k/v fragments for this head -> Bb[w], Cb[w] become free
    f16x8 qf[4], kf[4], vf[4];
#pragma unroll
    for (int it = 0; it < 4; ++it)
      qf[it] = ld8(&Bb[w * 2048 + (lg * TOK + it * 16 + l15) * 8]);
#pragma unroll
    for (int jt = 0; jt < 4; ++jt)
      kf[jt] = ld8(&Cb[w * 2048 + (lg * TOK + jt * 16 + l15) * 8]);
#pragma unroll
    for (int z = 0; z < 4; ++z) {  // z = ks*2+nt
      int ks = z >> 1, nt = z & 1;
      vf[z] = ld8(&Ab[w * 2048 + ((ks * 4 + lg) * HD + nt * 16 + l15) * 8]);
    }

#pragma unroll
    for (int it = 0; it < 4; ++it) {
      f32x4 st[4];
#pragma unroll
      for (int jt = 0; jt < 4; ++jt)
        st[jt] = __builtin_amdgcn_mfma_f32_16x16x32_f16(kf[jt], qf[it], vzero, 0, 0, 0);
      // bias: lane holds (i = it*16+l15, j = jt*16+lg*4+r)
      if constexpr (WS) {
        const _Float16* bw = ws + BIAS_OFF + ((w * 4 + it) * 64 + l) * 16;
        f16x8 b0 = ld8(bw), b1 = ld8(bw + 8);
#pragma unroll
        for (int jt = 0; jt < 4; ++jt)
#pragma unroll
          for (int r = 0; r < 4; ++r)
            st[jt][r] += (float)((jt < 2) ? b0[jt * 4 + r] : b1[(jt - 2) * 4 + r]);
      } else {
        int i = it * 16 + l15, yi = i >> 3, xi = i & 7;
#pragma unroll
        for (int jt = 0; jt < 4; ++jt)
#pragma unroll
          for (int r = 0; r < 4; ++r) {
            int j = jt * 16 + lg * 4 + r, yj = j >> 3, xj = j & 7;
            st[jt][r] += bias_sm[((yi - yj + 7) * 15 + (xi - xj + 7)) * NH + w];
          }
      }
      // softmax over row i (16 in-lane + lanes differing in lg)
      float m = st[0][0];
#pragma unroll
      for (int jt = 0; jt < 4; ++jt)
#pragma unroll
        for (int r = 0; r < 4; ++r) m = fmaxf(m, st[jt][r]);
      m = fmaxf(m, __shfl_xor(m, 16, 64));
      m = fmaxf(m, __shfl_xor(m, 32, 64));
      float e[4][4], sum = 0.f;
#pragma unroll
      for (int jt = 0; jt < 4; ++jt)
#pragma unroll
        for (int r = 0; r < 4; ++r) { e[jt][r] = __expf(st[jt][r] - m); sum += e[jt][r]; }
      sum += __shfl_xor(sum, 16, 64);
      sum += __shfl_xor(sum, 32, 64);
      float inv = 1.f / sum;
      // P -> Bb[w], double-buffered by (it&1); layout [jp][i16][j&7]
      _Float16* pbase = &Bb[w * 2048 + (it & 1) * 1024];
#pragma unroll
      for (int jt = 0; jt < 4; ++jt) {
        f16x4 pk;
#pragma unroll
        for (int r = 0; r < 4; ++r) pk[r] = (_Float16)(e[jt][r] * inv);
        *reinterpret_cast<f16x4*>(
            &pbase[((jt * 2 + (lg >> 1)) * 16 + l15) * 8 + (lg & 1) * 4]) = pk;
      }
      // PV: O[16x32] = P[16x64] @ V[64x32]
      f32x4 o[2] = {vzero, vzero};
#pragma unroll
      for (int ks = 0; ks < 2; ++ks) {
        f16x8 pf = ld8(&pbase[((ks * 4 + lg) * 16 + l15) * 8]);
#pragma unroll
        for (int nt = 0; nt < 2; ++nt)
          o[nt] = __builtin_amdgcn_mfma_f32_16x16x32_f16(pf, vf[ks * 2 + nt], o[nt], 0, 0, 0);
      }
      // O -> Cb (flat panel layout [c>>3][i][c&7]; head w block == Cb[w] region)
#pragma unroll
      for (int nt = 0; nt < 2; ++nt) {
        int c = w * HD + nt * 16 + l15;
#pragma unroll
        for (int r = 0; r < 4; ++r) {
          int i2 = it * 16 + lg * 4 + r;
          Cb[((c >> 3) * TOK + i2) * 8 + (c & 7)] = (_Float16)o[nt][r];
        }
      }
    }
  }
  __syncthreads();

  // ------- phase 3: projection (64x192, K=192); wave w -> e-tiles w, w+6 -------
  {
    f32x4 pacc[2][4];
#pragma unroll
    for (int g = 0; g < 2; ++g)
#pragma unroll
      for (int mt = 0; mt < 4; ++mt) pacc[g][mt] = vzero;
#pragma unroll
    for (int ks = 0; ks < 6; ++ks) {
      f16x8 a[4];
#pragma unroll
      for (int mt = 0; mt < 4; ++mt)
        a[mt] = ld8(&Cb[((ks * 4 + lg) * TOK + mt * 16 + l15) * 8]);
#pragma unroll
      for (int g = 0; g < 2; ++g) {
        int e = (w + 6 * g) * 16 + l15;
        f16x8 bf;
        if constexpr (WS) bf = ld8(ws + WP16_OFF + (size_t)e * CDIM + ks * 32 + lg * 8);
        else              bf = cvt8(w_proj + (size_t)e * CDIM + ks * 32 + lg * 8);
#pragma unroll
        for (int mt = 0; mt < 4; ++mt)
          pacc[g][mt] = __builtin_amdgcn_mfma_f32_16x16x32_f16(a[mt], bf, pacc[g][mt], 0, 0, 0);
      }
    }
#pragma unroll
    for (int g = 0; g < 2; ++g) {
      int e = (w + 6 * g) * 16 + l15;
      float bp = b_proj[e];
#pragma unroll
      for (int mt = 0; mt < 4; ++mt)
#pragma unroll
        for (int r = 0; r < 4; ++r) {
          int n = mt * 16 + lg * 4 + r;
          out[((size_t)b * TOK + n) * CDIM + e] = pacc[g][mt][r] + bp;
        }
    }
  }
}

extern "C" void kernel_launch(void* const* d_in, const int* in_sizes, int n_in,
                              void* d_out, int out_size, void* d_ws, size_t ws_size,
                              hipStream_t stream) {
  const float* x          = (const float*)d_in[0];
  const float* w_qkv      = (const float*)d_in[1];
  const float* b_qkv      = (const float*)d_in[2];
  const float* w_proj     = (const float*)d_in[3];
  const float* b_proj     = (const float*)d_in[4];
  const float* bias_table = (const float*)d_in[5];
  float* out = (float*)d_out;
  int B = in_sizes[0] / (TOK * CDIM);

  if (ws_size >= (size_t)WS_BYTES) {
    _Float16* ws = (_Float16*)d_ws;
    hipLaunchKernelGGL(prep_ws, dim3(240), dim3(256), 0, stream,
                       w_qkv, w_proj, bias_table, ws);
    hipLaunchKernelGGL(winattn<true>, dim3(B), dim3(THREADS), 0, stream,
                       x, w_qkv, b_qkv, w_proj, b_proj, bias_table, ws, out);
  } else {
    hipLaunchKernelGGL(winattn<false>, dim3(B), dim3(THREADS), 0, stream,
                       x, w_qkv, b_qkv, w_proj, b_proj, bias_table,
                       (const _Float16*)nullptr, out);
  }
}